// Round 6
// baseline (9019.880 us; speedup 1.0000x reference)
//
#include <hip/hip_runtime.h>
#include <math.h>

#define NN 100000
#define NE 1600000
#define HD 64
#define NG 256

__device__ __forceinline__ float rl(float v, int l) {
    return __int_as_float(__builtin_amdgcn_readlane(__float_as_int(v), l));
}

// ---------- layer-0 linear: m = x @ W0 ----------
__global__ __launch_bounds__(256) void k_lin0(const float* __restrict__ x,
                                              const float* __restrict__ W,
                                              float* __restrict__ m) {
    __shared__ float Wl[HD * HD];
    for (int i = threadIdx.x; i < HD * HD; i += 256) Wl[i] = W[i];
    __syncthreads();
    int lane = threadIdx.x & 63, wid = threadIdx.x >> 6;
    int step = gridDim.x * 4;
    for (int n = blockIdx.x * 4 + wid; n < NN; n += step) {
        float hv = x[(size_t)n * HD + lane];
        float acc = 0.f;
        #pragma unroll
        for (int k = 0; k < HD; ++k)
            acc = fmaf(rl(hv, k), Wl[k * HD + lane], acc);
        m[(size_t)n * HD + lane] = acc;
    }
}

// ---------- edge-parallel scatter, f32 atomics (proven 338us/layer) ----------
__global__ __launch_bounds__(256) void k_scat(const float* __restrict__ m,
                                              const int* __restrict__ ei,
                                              float* __restrict__ agg) {
    long long tid = (long long)blockIdx.x * 256 + threadIdx.x;
    long long stride = (long long)gridDim.x * 256;
    const long long total = (long long)NE * HD;
    for (long long i = tid; i < total; i += stride) {
        int e = (int)(i >> 6);
        int c = (int)(i & 63);
        int s = ei[e];
        int d = ei[NE + e];
        atomicAdd(&agg[(size_t)d * HD + c], m[(size_t)s * HD + c]);
    }
}

// ---------- fused cell: gi + gh + GRU + next-layer linear ----------
// WT row stride R=385 (R%32==1): transpose-staging writes are conflict-free,
// row reads are consecutive-lane -> conflict-free.
__global__ __launch_bounds__(1024) void k_cell(const float* __restrict__ agg,
                                               const float* __restrict__ Wih,
                                               const float* __restrict__ Whh,
                                               const float* __restrict__ bih,
                                               const float* __restrict__ bhh,
                                               const float* __restrict__ h_in,
                                               float* __restrict__ h_out,
                                               const float* __restrict__ Wnext,
                                               float* __restrict__ m_next,
                                               int has_next) {
    const int R = 385;
    __shared__ float WT[HD * R];
    __shared__ float WL[HD * HD];
    for (int i = threadIdx.x; i < 192 * HD; i += 1024) {
        int j = i >> 6, k = i & 63;           // Wih[j][k], coalesced read
        WT[k * R + j] = Wih[i];
    }
    for (int i = threadIdx.x; i < 192 * HD; i += 1024) {
        int j = i >> 6, k = i & 63;
        WT[k * R + 192 + j] = Whh[i];
    }
    if (has_next)
        for (int i = threadIdx.x; i < HD * HD; i += 1024) WL[i] = Wnext[i];
    __syncthreads();

    int lane = threadIdx.x & 63;
    int gw = blockIdx.x * 16 + (threadIdx.x >> 6);
    const int nwaves = gridDim.x * 16;

    float bi0 = bih[lane], bi1 = bih[64 + lane], bi2 = bih[128 + lane];
    float bh0 = bhh[lane], bh1 = bhh[64 + lane], bh2 = bhh[128 + lane];

    for (int n = gw; n < NN; n += nwaves) {
        float av = agg[(size_t)n * HD + lane];
        float hv = h_in[(size_t)n * HD + lane];

        float a0 = bi0, a1 = bi1, a2 = bi2;
        float g0 = bh0, g1 = bh1, g2 = bh2;
        #pragma unroll
        for (int k = 0; k < HD; ++k) {
            float ak = rl(av, k);
            float hk = rl(hv, k);
            const float* w = &WT[k * R];
            a0 = fmaf(ak, w[lane], a0);
            a1 = fmaf(ak, w[64 + lane], a1);
            a2 = fmaf(ak, w[128 + lane], a2);
            g0 = fmaf(hk, w[192 + lane], g0);
            g1 = fmaf(hk, w[256 + lane], g1);
            g2 = fmaf(hk, w[320 + lane], g2);
        }

        float r = 1.f / (1.f + expf(-(a0 + g0)));
        float z = 1.f / (1.f + expf(-(a1 + g1)));
        float nq = tanhf(a2 + r * g2);
        float hnew = (1.f - z) * nq + z * hv;
        h_out[(size_t)n * HD + lane] = hnew;

        if (has_next) {
            float acc = 0.f;
            #pragma unroll
            for (int k = 0; k < HD; ++k)
                acc = fmaf(rl(hnew, k), WL[k * HD + lane], acc);
            m_next[(size_t)n * HD + lane] = acc;
        }
    }
}

// ---------- pool: batch sorted, per-wave contiguous range ----------
__global__ __launch_bounds__(256) void k_pool(const float* __restrict__ h,
                                              const int* __restrict__ batch,
                                              float* __restrict__ out) {
    int gw = (int)((blockIdx.x * 256 + threadIdx.x) >> 6);
    int lane = threadIdx.x & 63;
    int nw = (gridDim.x * 256) >> 6;
    int per = (NN + nw - 1) / nw;
    int s = gw * per;
    int e = s + per; if (e > NN) e = NN;
    if (s >= NN) return;
    float acc = 0.f;
    int cur = batch[s];
    for (int n = s; n < e; ++n) {
        int b = batch[n];
        if (b != cur) {
            atomicAdd(&out[cur * HD + lane], acc);
            acc = 0.f; cur = b;
        }
        acc += h[n * HD + lane];
    }
    atomicAdd(&out[cur * HD + lane], acc);
}

extern "C" void kernel_launch(void* const* d_in, const int* in_sizes, int n_in,
                              void* d_out, int out_size, void* d_ws, size_t ws_size,
                              hipStream_t stream) {
    const float* x      = (const float*)d_in[0];
    const int*   ei     = (const int*)d_in[1];
    const int*   batch  = (const int*)d_in[2];
    const float* weight = (const float*)d_in[3];
    const float* Wih    = (const float*)d_in[4];
    const float* Whh    = (const float*)d_in[5];
    const float* bih    = (const float*)d_in[6];
    const float* bhh    = (const float*)d_in[7];
    float* out = (float*)d_out;

    char* ws = (char*)d_ws;
    const size_t szH = (size_t)NN * HD * sizeof(float);    // 25.6 MB
    float* H  = (float*)(ws);
    float* MA = (float*)(ws + szH);
    float* MB = (float*)(ws + 2 * szH);
    float* AG = (float*)(ws + 3 * szH);

    // layer 0 messages from x
    k_lin0<<<1024, 256, 0, stream>>>(x, weight, MA);

    // layer 1
    hipMemsetAsync(AG, 0, szH, stream);
    k_scat<<<2048, 256, 0, stream>>>(MA, ei, AG);
    k_cell<<<256, 1024, 0, stream>>>(AG, Wih, Whh, bih, bhh, x, H,
                                     weight + 1 * HD * HD, MB, 1);
    // layer 2
    hipMemsetAsync(AG, 0, szH, stream);
    k_scat<<<2048, 256, 0, stream>>>(MB, ei, AG);
    k_cell<<<256, 1024, 0, stream>>>(AG, Wih, Whh, bih, bhh, H, H,
                                     weight + 2 * HD * HD, MA, 1);
    // layer 3
    hipMemsetAsync(AG, 0, szH, stream);
    k_scat<<<2048, 256, 0, stream>>>(MA, ei, AG);
    k_cell<<<256, 1024, 0, stream>>>(AG, Wih, Whh, bih, bhh, H, H,
                                     nullptr, nullptr, 0);

    hipMemsetAsync(out, 0, (size_t)NG * HD * sizeof(float), stream);
    k_pool<<<512, 256, 0, stream>>>(H, batch, out);
}

// Round 7
// 1777.328 us; speedup vs baseline: 5.0750x; 5.0750x over previous
//
#include <hip/hip_runtime.h>
#include <math.h>

#define NN 100000
#define NE 1600000
#define HD 64
#define NG 256

// ---------- CSR build (one-time; edge_index constant across layers) ----------
__global__ __launch_bounds__(256) void k_deg(const int* __restrict__ ei, int* __restrict__ deg) {
    int tid = blockIdx.x * 256 + threadIdx.x;
    int stride = gridDim.x * 256;
    for (int e = tid; e < NE; e += stride)
        atomicAdd(&deg[ei[NE + e]], 1);
}

__global__ __launch_bounds__(1024) void k_scan(const int* __restrict__ deg,
                                               int* __restrict__ cursor) {
    __shared__ int buf[1024];
    __shared__ int s_carry;
    if (threadIdx.x == 0) s_carry = 0;
    __syncthreads();
    for (int base = 0; base < NN; base += 4096) {
        int idx = base + threadIdx.x * 4;
        int d0 = 0, d1 = 0, d2 = 0, d3 = 0;
        if (idx + 3 < NN) {
            const int4 v = *(const int4*)(deg + idx);
            d0 = v.x; d1 = v.y; d2 = v.z; d3 = v.w;
        } else {
            if (idx < NN) d0 = deg[idx];
            if (idx + 1 < NN) d1 = deg[idx + 1];
            if (idx + 2 < NN) d2 = deg[idx + 2];
        }
        int tsum = d0 + d1 + d2 + d3;
        buf[threadIdx.x] = tsum;
        __syncthreads();
        for (int off = 1; off < 1024; off <<= 1) {
            int t = (threadIdx.x >= off) ? buf[threadIdx.x - off] : 0;
            __syncthreads();
            buf[threadIdx.x] += t;
            __syncthreads();
        }
        int incl = buf[threadIdx.x];
        int carry = s_carry;
        int e0 = incl - tsum + carry;
        int e1 = e0 + d0, e2 = e1 + d1, e3 = e2 + d2;
        if (idx < NN)     cursor[idx] = e0;
        if (idx + 1 < NN) cursor[idx + 1] = e1;
        if (idx + 2 < NN) cursor[idx + 2] = e2;
        if (idx + 3 < NN) cursor[idx + 3] = e3;
        __syncthreads();
        if (threadIdx.x == 0) s_carry += buf[1023];
        __syncthreads();
    }
}

__global__ __launch_bounds__(256) void k_fill(const int* __restrict__ ei,
                                              int* __restrict__ cursor,
                                              int2* __restrict__ epack) {
    int tid = blockIdx.x * 256 + threadIdx.x;
    int stride = gridDim.x * 256;
    for (int e = tid; e < NE; e += stride) {
        int s = ei[e];
        int d = ei[NE + e];
        int pos = atomicAdd(&cursor[d], 1);
        epack[pos] = make_int2(s, d);
    }
}

// ---------- m = h @ W (R2-proven) ----------
__global__ __launch_bounds__(256) void k_lin(const float* __restrict__ h,
                                             const float* __restrict__ W,
                                             float* __restrict__ m) {
    __shared__ float Wl[HD * HD];
    for (int i = threadIdx.x; i < HD * HD; i += 256) Wl[i] = W[i];
    __syncthreads();
    int lane = threadIdx.x & 63, wid = threadIdx.x >> 6;
    int step = gridDim.x * 4;
    for (int n = blockIdx.x * 4 + wid; n < NN; n += step) {
        float hv = h[(size_t)n * HD + lane];
        float acc = 0.f;
        #pragma unroll
        for (int k = 0; k < HD; ++k)
            acc = fmaf(__shfl(hv, k, 64), Wl[k * HD + lane], acc);
        m[(size_t)n * HD + lane] = acc;
    }
}

// ---------- edge-parallel segmented gather over dst-sorted edges (R4 piece) ----------
__global__ __launch_bounds__(256) void k_gather(const float* __restrict__ m,
                                                const int2* __restrict__ epack,
                                                float* __restrict__ agg) {
    int gw = (int)((blockIdx.x * 256 + threadIdx.x) >> 6);
    int lane = threadIdx.x & 63;
    int nw = (gridDim.x * 256) >> 6;
    int per = (NE + nw - 1) / nw;
    int s = gw * per;
    int e = s + per; if (e > NE) e = NE;
    if (s >= NE) return;

    float acc = 0.f;
    int cur = epack[s].y;
    int i = s;
    for (; i + 4 <= e; i += 4) {
        int2 p0 = epack[i], p1 = epack[i + 1], p2 = epack[i + 2], p3 = epack[i + 3];
        float v0 = m[(size_t)p0.x * HD + lane];
        float v1 = m[(size_t)p1.x * HD + lane];
        float v2 = m[(size_t)p2.x * HD + lane];
        float v3 = m[(size_t)p3.x * HD + lane];
        if (p0.y != cur) { atomicAdd(&agg[(size_t)cur * HD + lane], acc); acc = 0.f; cur = p0.y; }
        acc += v0;
        if (p1.y != cur) { atomicAdd(&agg[(size_t)cur * HD + lane], acc); acc = 0.f; cur = p1.y; }
        acc += v1;
        if (p2.y != cur) { atomicAdd(&agg[(size_t)cur * HD + lane], acc); acc = 0.f; cur = p2.y; }
        acc += v2;
        if (p3.y != cur) { atomicAdd(&agg[(size_t)cur * HD + lane], acc); acc = 0.f; cur = p3.y; }
        acc += v3;
    }
    for (; i < e; ++i) {
        int2 p = epack[i];
        float v = m[(size_t)p.x * HD + lane];
        if (p.y != cur) { atomicAdd(&agg[(size_t)cur * HD + lane], acc); acc = 0.f; cur = p.y; }
        acc += v;
    }
    atomicAdd(&agg[(size_t)cur * HD + lane], acc);
}

// ---------- gi = agg @ Wih^T + bih (R2-proven shape: 256thr, 48KB LDS) ----------
__global__ __launch_bounds__(256) void k_gi(const float* __restrict__ agg,
                                            const float* __restrict__ Wih,
                                            const float* __restrict__ bih,
                                            float* __restrict__ gi) {
    __shared__ float WT[HD * 192];
    for (int i = threadIdx.x; i < HD * 192; i += 256) {
        int k = i / 192, j = i % 192;
        WT[i] = Wih[j * HD + k];
    }
    __syncthreads();
    int lane = threadIdx.x & 63, wid = threadIdx.x >> 6;
    float b0 = bih[lane], b1 = bih[64 + lane], b2 = bih[128 + lane];
    int step = gridDim.x * 4;
    for (int n = blockIdx.x * 4 + wid; n < NN; n += step) {
        float av = agg[(size_t)n * HD + lane];
        float a0 = b0, a1 = b1, a2 = b2;
        #pragma unroll
        for (int k = 0; k < HD; ++k) {
            float ak = __shfl(av, k, 64);
            a0 = fmaf(ak, WT[k * 192 + lane], a0);
            a1 = fmaf(ak, WT[k * 192 + 64 + lane], a1);
            a2 = fmaf(ak, WT[k * 192 + 128 + lane], a2);
        }
        gi[(size_t)n * 192 + lane] = a0;
        gi[(size_t)n * 192 + 64 + lane] = a1;
        gi[(size_t)n * 192 + 128 + lane] = a2;
    }
}

// ---------- gh + GRU pointwise, h in place (R2-proven shape) ----------
__global__ __launch_bounds__(256) void k_gru(const float* __restrict__ gi,
                                             const float* __restrict__ Whh,
                                             const float* __restrict__ bhh,
                                             float* __restrict__ h) {
    __shared__ float WT[HD * 192];
    for (int i = threadIdx.x; i < HD * 192; i += 256) {
        int k = i / 192, j = i % 192;
        WT[i] = Whh[j * HD + k];
    }
    __syncthreads();
    int lane = threadIdx.x & 63, wid = threadIdx.x >> 6;
    float b0 = bhh[lane], b1 = bhh[64 + lane], b2 = bhh[128 + lane];
    int step = gridDim.x * 4;
    for (int n = blockIdx.x * 4 + wid; n < NN; n += step) {
        float hv = h[(size_t)n * HD + lane];
        float g0 = b0, g1 = b1, g2 = b2;
        #pragma unroll
        for (int k = 0; k < HD; ++k) {
            float hk = __shfl(hv, k, 64);
            g0 = fmaf(hk, WT[k * 192 + lane], g0);
            g1 = fmaf(hk, WT[k * 192 + 64 + lane], g1);
            g2 = fmaf(hk, WT[k * 192 + 128 + lane], g2);
        }
        float ir = gi[(size_t)n * 192 + lane];
        float iz = gi[(size_t)n * 192 + 64 + lane];
        float inn = gi[(size_t)n * 192 + 128 + lane];
        float r = 1.f / (1.f + expf(-(ir + g0)));
        float z = 1.f / (1.f + expf(-(iz + g1)));
        float nn = tanhf(inn + r * g2);
        h[(size_t)n * HD + lane] = (1.f - z) * nn + z * hv;
    }
}

// ---------- pool: batch sorted, per-wave contiguous range ----------
__global__ __launch_bounds__(256) void k_pool(const float* __restrict__ h,
                                              const int* __restrict__ batch,
                                              float* __restrict__ out) {
    int gw = (int)((blockIdx.x * 256 + threadIdx.x) >> 6);
    int lane = threadIdx.x & 63;
    int nw = (gridDim.x * 256) >> 6;
    int per = (NN + nw - 1) / nw;
    int s = gw * per;
    int e = s + per; if (e > NN) e = NN;
    if (s >= NN) return;
    float acc = 0.f;
    int cur = batch[s];
    for (int n = s; n < e; ++n) {
        int b = batch[n];
        if (b != cur) {
            atomicAdd(&out[cur * HD + lane], acc);
            acc = 0.f; cur = b;
        }
        acc += h[n * HD + lane];
    }
    atomicAdd(&out[cur * HD + lane], acc);
}

extern "C" void kernel_launch(void* const* d_in, const int* in_sizes, int n_in,
                              void* d_out, int out_size, void* d_ws, size_t ws_size,
                              hipStream_t stream) {
    const float* x      = (const float*)d_in[0];
    const int*   ei     = (const int*)d_in[1];
    const int*   batch  = (const int*)d_in[2];
    const float* weight = (const float*)d_in[3];
    const float* Wih    = (const float*)d_in[4];
    const float* Whh    = (const float*)d_in[5];
    const float* bih    = (const float*)d_in[6];
    const float* bhh    = (const float*)d_in[7];
    float* out = (float*)d_out;

    char* ws = (char*)d_ws;
    const size_t szH = (size_t)NN * HD * sizeof(float);   // 25.6 MB
    float* H  = (float*)(ws);
    float* M  = (float*)(ws + szH);
    float* AG = (float*)(ws + 2 * szH);
    float* GI = (float*)(ws + 3 * szH);                    // 76.8 MB
    int*   deg    = (int*)(ws + 6 * szH);
    int*   cursor = deg + NN;
    int2*  epack  = (int2*)(cursor + NN);                  // 12.8 MB

    // CSR build
    hipMemsetAsync(deg, 0, NN * sizeof(int), stream);
    k_deg<<<2048, 256, 0, stream>>>(ei, deg);
    k_scan<<<1, 1024, 0, stream>>>(deg, cursor);
    k_fill<<<2048, 256, 0, stream>>>(ei, cursor, epack);

    hipMemcpyAsync(H, x, szH, hipMemcpyDeviceToDevice, stream);

    const float* Ws[3] = { weight, weight + HD * HD, weight + 2 * HD * HD };
    for (int l = 0; l < 3; ++l) {
        k_lin<<<1024, 256, 0, stream>>>(H, Ws[l], M);
        hipMemsetAsync(AG, 0, szH, stream);
        k_gather<<<2048, 256, 0, stream>>>(M, epack, AG);
        k_gi<<<1024, 256, 0, stream>>>(AG, Wih, bih, GI);
        k_gru<<<1024, 256, 0, stream>>>(GI, Whh, bhh, H);
    }

    hipMemsetAsync(out, 0, (size_t)NG * HD * sizeof(float), stream);
    k_pool<<<512, 256, 0, stream>>>(H, batch, out);
}

// Round 9
// 1036.253 us; speedup vs baseline: 8.7043x; 1.7151x over previous
//
#include <hip/hip_runtime.h>
#include <math.h>

#define NN 100000
#define NE 1600000
#define HD 64
#define NG 256

typedef _Float16 half2v __attribute__((ext_vector_type(2)));

__device__ __forceinline__ unsigned pkh2(float a, float b) {
    return __builtin_bit_cast(unsigned, __builtin_amdgcn_cvt_pkrtz(a, b));
}

__device__ __forceinline__ float dot2(float acc, unsigned a, unsigned b) {
#if __has_builtin(__builtin_amdgcn_fdot2)
    return __builtin_amdgcn_fdot2(__builtin_bit_cast(half2v, a),
                                  __builtin_bit_cast(half2v, b), acc, false);
#else
    asm("v_dot2_f32_f16 %0, %1, %2, %0" : "+v"(acc) : "v"(a), "v"(b));
    return acc;
#endif
}

__device__ __forceinline__ unsigned rlu(unsigned v, int l) {
    return (unsigned)__builtin_amdgcn_readlane((int)v, l);
}

// ---------- CSR build (proven) ----------
__global__ __launch_bounds__(256) void k_deg(const int* __restrict__ ei, int* __restrict__ deg) {
    int tid = blockIdx.x * 256 + threadIdx.x;
    int stride = gridDim.x * 256;
    for (int e = tid; e < NE; e += stride)
        atomicAdd(&deg[ei[NE + e]], 1);
}

__global__ __launch_bounds__(1024) void k_scan(const int* __restrict__ deg,
                                               int* __restrict__ cursor) {
    __shared__ int buf[1024];
    __shared__ int s_carry;
    if (threadIdx.x == 0) s_carry = 0;
    __syncthreads();
    for (int base = 0; base < NN; base += 4096) {
        int idx = base + threadIdx.x * 4;
        int d0 = 0, d1 = 0, d2 = 0, d3 = 0;
        if (idx + 3 < NN) {
            const int4 v = *(const int4*)(deg + idx);
            d0 = v.x; d1 = v.y; d2 = v.z; d3 = v.w;
        } else {
            if (idx < NN) d0 = deg[idx];
            if (idx + 1 < NN) d1 = deg[idx + 1];
            if (idx + 2 < NN) d2 = deg[idx + 2];
        }
        int tsum = d0 + d1 + d2 + d3;
        buf[threadIdx.x] = tsum;
        __syncthreads();
        for (int off = 1; off < 1024; off <<= 1) {
            int t = (threadIdx.x >= off) ? buf[threadIdx.x - off] : 0;
            __syncthreads();
            buf[threadIdx.x] += t;
            __syncthreads();
        }
        int incl = buf[threadIdx.x];
        int carry = s_carry;
        int e0 = incl - tsum + carry;
        int e1 = e0 + d0, e2 = e1 + d1, e3 = e2 + d2;
        if (idx < NN)     cursor[idx] = e0;
        if (idx + 1 < NN) cursor[idx + 1] = e1;
        if (idx + 2 < NN) cursor[idx + 2] = e2;
        if (idx + 3 < NN) cursor[idx + 3] = e3;
        __syncthreads();
        if (threadIdx.x == 0) s_carry += buf[1023];
        __syncthreads();
    }
}

__global__ __launch_bounds__(256) void k_fill(const int* __restrict__ ei,
                                              int* __restrict__ cursor,
                                              int2* __restrict__ epack) {
    int tid = blockIdx.x * 256 + threadIdx.x;
    int stride = gridDim.x * 256;
    for (int e = tid; e < NE; e += stride) {
        int s = ei[e];
        int d = ei[NE + e];
        int pos = atomicAdd(&cursor[d], 1);
        epack[pos] = make_int2(s, d);
    }
}

// ---------- layer-0 linear on x (f32, proven) ----------
__global__ __launch_bounds__(256) void k_lin(const float* __restrict__ h,
                                             const float* __restrict__ W,
                                             float* __restrict__ m) {
    __shared__ float Wl[HD * HD];
    for (int i = threadIdx.x; i < HD * HD; i += 256) Wl[i] = W[i];
    __syncthreads();
    int lane = threadIdx.x & 63, wid = threadIdx.x >> 6;
    int step = gridDim.x * 4;
    for (int n = blockIdx.x * 4 + wid; n < NN; n += step) {
        float hv = h[(size_t)n * HD + lane];
        float acc = 0.f;
        #pragma unroll
        for (int k = 0; k < HD; ++k)
            acc = fmaf(__shfl(hv, k, 64), Wl[k * HD + lane], acc);
        m[(size_t)n * HD + lane] = acc;
    }
}

// ---------- dot2 linear from packed-f16 h (layers 1,2) ----------
// WL[kk][c] = pack(W[2kk][c], W[2kk+1][c]); row stride 65 -> conflict-free.
__global__ __launch_bounds__(256) void k_lin2(const unsigned* __restrict__ hq,
                                              const float* __restrict__ W,
                                              float* __restrict__ m) {
    __shared__ unsigned WL[32 * 65];
    for (int i = threadIdx.x; i < 32 * 64; i += 256) {
        int kk = i >> 6, c = i & 63;
        WL[kk * 65 + c] = pkh2(W[(2 * kk) * HD + c], W[(2 * kk + 1) * HD + c]);
    }
    __syncthreads();
    int lane = threadIdx.x & 63, wid = threadIdx.x >> 6;
    int step = gridDim.x * 4;
    for (int n = blockIdx.x * 4 + wid; n < NN; n += step) {
        unsigned hv = hq[(size_t)n * 32 + (lane & 31)];
        float acc = 0.f;
        #pragma unroll 8
        for (int kk = 0; kk < 32; ++kk)
            acc = dot2(acc, rlu(hv, kk), WL[kk * 65 + lane]);
        m[(size_t)n * HD + lane] = acc;
    }
}

// ---------- edge-parallel segmented gather over dst-sorted edges (proven) ----------
__global__ __launch_bounds__(256) void k_gather(const float* __restrict__ m,
                                                const int2* __restrict__ epack,
                                                float* __restrict__ agg) {
    int gw = (int)((blockIdx.x * 256 + threadIdx.x) >> 6);
    int lane = threadIdx.x & 63;
    int nw = (gridDim.x * 256) >> 6;
    int per = (NE + nw - 1) / nw;
    int s = gw * per;
    int e = s + per; if (e > NE) e = NE;
    if (s >= NE) return;

    float acc = 0.f;
    int cur = epack[s].y;
    int i = s;
    for (; i + 4 <= e; i += 4) {
        int2 p0 = epack[i], p1 = epack[i + 1], p2 = epack[i + 2], p3 = epack[i + 3];
        float v0 = m[(size_t)p0.x * HD + lane];
        float v1 = m[(size_t)p1.x * HD + lane];
        float v2 = m[(size_t)p2.x * HD + lane];
        float v3 = m[(size_t)p3.x * HD + lane];
        if (p0.y != cur) { atomicAdd(&agg[(size_t)cur * HD + lane], acc); acc = 0.f; cur = p0.y; }
        acc += v0;
        if (p1.y != cur) { atomicAdd(&agg[(size_t)cur * HD + lane], acc); acc = 0.f; cur = p1.y; }
        acc += v1;
        if (p2.y != cur) { atomicAdd(&agg[(size_t)cur * HD + lane], acc); acc = 0.f; cur = p2.y; }
        acc += v2;
        if (p3.y != cur) { atomicAdd(&agg[(size_t)cur * HD + lane], acc); acc = 0.f; cur = p3.y; }
        acc += v3;
    }
    for (; i < e; ++i) {
        int2 p = epack[i];
        float v = m[(size_t)p.x * HD + lane];
        if (p.y != cur) { atomicAdd(&agg[(size_t)cur * HD + lane], acc); acc = 0.f; cur = p.y; }
        acc += v;
    }
    atomicAdd(&agg[(size_t)cur * HD + lane], acc);
}

// ---------- fused cell: gi + gh + GRU via packed-f16 dot2 ----------
// WT[kk][j], row stride 385: j in [0,192) = pack(Wih[j][2kk],Wih[j][2kk+1]),
//                            j in [192,384) = same for Whh.
__global__ __launch_bounds__(256) void k_cell(const float* __restrict__ agg,
                                              const float* __restrict__ Wih,
                                              const float* __restrict__ Whh,
                                              const float* __restrict__ bih,
                                              const float* __restrict__ bhh,
                                              const float* __restrict__ h_in,
                                              float* __restrict__ h_out,
                                              unsigned* __restrict__ hpk_out,
                                              int write_pk) {
    __shared__ unsigned WT[32 * 385];
    const float2* A2 = (const float2*)Wih;   // [192][32] float2
    const float2* H2 = (const float2*)Whh;
    for (int i = threadIdx.x; i < 192 * 32; i += 256) {
        int j = i >> 5, kk = i & 31;
        float2 w = A2[i];
        WT[kk * 385 + j] = pkh2(w.x, w.y);
    }
    for (int i = threadIdx.x; i < 192 * 32; i += 256) {
        int j = i >> 5, kk = i & 31;
        float2 w = H2[i];
        WT[kk * 385 + 192 + j] = pkh2(w.x, w.y);
    }
    __syncthreads();

    int lane = threadIdx.x & 63, wid = threadIdx.x >> 6;
    int step = gridDim.x * 4;
    float bi0 = bih[lane], bi1 = bih[64 + lane], bi2 = bih[128 + lane];
    float bh0 = bhh[lane], bh1 = bhh[64 + lane], bh2 = bhh[128 + lane];

    for (int n = blockIdx.x * 4 + wid; n < NN; n += step) {
        float av = agg[(size_t)n * HD + lane];
        float hv = h_in[(size_t)n * HD + lane];
        unsigned apk = pkh2(av, __shfl_xor(av, 1, 64));
        unsigned hpk = pkh2(hv, __shfl_xor(hv, 1, 64));

        float a0 = bi0, a1 = bi1, a2 = bi2;
        float g0 = bh0, g1 = bh1, g2 = bh2;
        #pragma unroll 8
        for (int kk = 0; kk < 32; ++kk) {
            unsigned au = rlu(apk, 2 * kk);
            unsigned hu = rlu(hpk, 2 * kk);
            const unsigned* w = &WT[kk * 385];
            a0 = dot2(a0, au, w[lane]);
            a1 = dot2(a1, au, w[64 + lane]);
            a2 = dot2(a2, au, w[128 + lane]);
            g0 = dot2(g0, hu, w[192 + lane]);
            g1 = dot2(g1, hu, w[256 + lane]);
            g2 = dot2(g2, hu, w[320 + lane]);
        }

        float r = 1.f / (1.f + expf(-(a0 + g0)));
        float z = 1.f / (1.f + expf(-(a1 + g1)));
        float nq = tanhf(a2 + r * g2);
        float hnew = (1.f - z) * nq + z * hv;
        h_out[(size_t)n * HD + lane] = hnew;

        if (write_pk) {
            unsigned o = pkh2(hnew, __shfl_xor(hnew, 1, 64));
            if (!(lane & 1)) hpk_out[(size_t)n * 32 + (lane >> 1)] = o;
        }
    }
}

// ---------- pool (proven) ----------
__global__ __launch_bounds__(256) void k_pool(const float* __restrict__ h,
                                              const int* __restrict__ batch,
                                              float* __restrict__ out) {
    int gw = (int)((blockIdx.x * 256 + threadIdx.x) >> 6);
    int lane = threadIdx.x & 63;
    int nw = (gridDim.x * 256) >> 6;
    int per = (NN + nw - 1) / nw;
    int s = gw * per;
    int e = s + per; if (e > NN) e = NN;
    if (s >= NN) return;
    float acc = 0.f;
    int cur = batch[s];
    for (int n = s; n < e; ++n) {
        int b = batch[n];
        if (b != cur) {
            atomicAdd(&out[cur * HD + lane], acc);
            acc = 0.f; cur = b;
        }
        acc += h[n * HD + lane];
    }
    atomicAdd(&out[cur * HD + lane], acc);
}

extern "C" void kernel_launch(void* const* d_in, const int* in_sizes, int n_in,
                              void* d_out, int out_size, void* d_ws, size_t ws_size,
                              hipStream_t stream) {
    const float* x      = (const float*)d_in[0];
    const int*   ei     = (const int*)d_in[1];
    const int*   batch  = (const int*)d_in[2];
    const float* weight = (const float*)d_in[3];
    const float* Wih    = (const float*)d_in[4];
    const float* Whh    = (const float*)d_in[5];
    const float* bih    = (const float*)d_in[6];
    const float* bhh    = (const float*)d_in[7];
    float* out = (float*)d_out;

    char* ws = (char*)d_ws;
    const size_t szH = (size_t)NN * HD * sizeof(float);    // 25.6 MB
    const size_t szP = (size_t)NN * 32 * sizeof(unsigned); // 12.8 MB
    float*    H   = (float*)(ws);
    float*    M   = (float*)(ws + szH);
    float*    AG  = (float*)(ws + 2 * szH);
    unsigned* HP  = (unsigned*)(ws + 3 * szH);
    int*   deg    = (int*)(ws + 3 * szH + szP);
    int*   cursor = deg + NN;
    int2*  epack  = (int2*)(cursor + NN);                  // 12.8 MB

    // CSR build
    hipMemsetAsync(deg, 0, NN * sizeof(int), stream);
    k_deg<<<2048, 256, 0, stream>>>(ei, deg);
    k_scan<<<1, 1024, 0, stream>>>(deg, cursor);
    k_fill<<<2048, 256, 0, stream>>>(ei, cursor, epack);

    // layer 0
    k_lin<<<1024, 256, 0, stream>>>(x, weight, M);
    hipMemsetAsync(AG, 0, szH, stream);
    k_gather<<<2048, 256, 0, stream>>>(M, epack, AG);
    k_cell<<<768, 256, 0, stream>>>(AG, Wih, Whh, bih, bhh, x, H, HP, 1);

    // layer 1
    k_lin2<<<1024, 256, 0, stream>>>(HP, weight + HD * HD, M);
    hipMemsetAsync(AG, 0, szH, stream);
    k_gather<<<2048, 256, 0, stream>>>(M, epack, AG);
    k_cell<<<768, 256, 0, stream>>>(AG, Wih, Whh, bih, bhh, H, H, HP, 1);

    // layer 2
    k_lin2<<<1024, 256, 0, stream>>>(HP, weight + 2 * HD * HD, M);
    hipMemsetAsync(AG, 0, szH, stream);
    k_gather<<<2048, 256, 0, stream>>>(M, epack, AG);
    k_cell<<<768, 256, 0, stream>>>(AG, Wih, Whh, bih, bhh, H, H, HP, 0);

    hipMemsetAsync(out, 0, (size_t)NG * HD * sizeof(float), stream);
    k_pool<<<512, 256, 0, stream>>>(H, batch, out);
}

// Round 12
// 924.724 us; speedup vs baseline: 9.7541x; 1.1206x over previous
//
#include <hip/hip_runtime.h>
#include <math.h>

#define NN 100000
#define NE 1600000
#define HD 64
#define NG 256
#define NSB ((NN + 1023) / 1024)   // 98 scan blocks

typedef _Float16 half2v __attribute__((ext_vector_type(2)));

__device__ __forceinline__ unsigned pkh2(float a, float b) {
    return __builtin_bit_cast(unsigned, __builtin_amdgcn_cvt_pkrtz(a, b));
}
__device__ __forceinline__ unsigned short f2h(float a) {
    union { _Float16 f; unsigned short s; } c; c.f = (_Float16)a; return c.s;
}
__device__ __forceinline__ float h2f(unsigned short s) {
    union { unsigned short s; _Float16 f; } c; c.s = s; return (float)c.f;
}
__device__ __forceinline__ float dot2(float acc, unsigned a, unsigned b) {
#if __has_builtin(__builtin_amdgcn_fdot2)
    return __builtin_amdgcn_fdot2(__builtin_bit_cast(half2v, a),
                                  __builtin_bit_cast(half2v, b), acc, false);
#else
    asm("v_dot2_f32_f16 %0, %1, %2, %0" : "+v"(acc) : "v"(a), "v"(b));
    return acc;
#endif
}
__device__ __forceinline__ unsigned rlu(unsigned v, int l) {
    return (unsigned)__builtin_amdgcn_readlane((int)v, l);
}

// ---------- CSR build ----------
__global__ __launch_bounds__(256) void k_deg(const int* __restrict__ ei, int* __restrict__ deg) {
    int tid = blockIdx.x * 256 + threadIdx.x;
    int stride = gridDim.x * 256;
    for (int e = tid; e < NE; e += stride)
        atomicAdd(&deg[ei[NE + e]], 1);
}

// multi-block scan: a) per-block exclusive scan + block sum
__global__ __launch_bounds__(1024) void k_scan_a(const int* __restrict__ deg,
                                                 int* __restrict__ cursor,
                                                 int* __restrict__ bsum) {
    __shared__ int buf[1024];
    int t = threadIdx.x;
    int idx = blockIdx.x * 1024 + t;
    int v = (idx < NN) ? deg[idx] : 0;
    buf[t] = v;
    __syncthreads();
    for (int off = 1; off < 1024; off <<= 1) {
        int x = (t >= off) ? buf[t - off] : 0;
        __syncthreads();
        buf[t] += x;
        __syncthreads();
    }
    if (idx < NN) cursor[idx] = buf[t] - v;
    if (t == 1023) bsum[blockIdx.x] = buf[t];
}
// b) single-block exclusive scan of the 98 block sums
__global__ __launch_bounds__(128) void k_scan_b(int* __restrict__ bsum) {
    __shared__ int buf[128];
    int t = threadIdx.x;
    int v = (t < NSB) ? bsum[t] : 0;
    buf[t] = v;
    __syncthreads();
    for (int off = 1; off < 128; off <<= 1) {
        int x = (t >= off) ? buf[t - off] : 0;
        __syncthreads();
        buf[t] += x;
        __syncthreads();
    }
    if (t < NSB) bsum[t] = buf[t] - v;
}
// c) add block offsets
__global__ __launch_bounds__(1024) void k_scan_c(int* __restrict__ cursor,
                                                 const int* __restrict__ bsum) {
    int idx = blockIdx.x * 1024 + threadIdx.x;
    if (idx < NN) cursor[idx] += bsum[blockIdx.x];
}

__global__ __launch_bounds__(256) void k_fill(const int* __restrict__ ei,
                                              int* __restrict__ cursor,
                                              int2* __restrict__ epack) {
    int tid = blockIdx.x * 256 + threadIdx.x;
    int stride = gridDim.x * 256;
    for (int e = tid; e < NE; e += stride) {
        int s = ei[e];
        int d = ei[NE + e];
        int pos = atomicAdd(&cursor[d], 1);
        epack[pos] = make_int2(s, d);
    }
}

// ---------- layer-0 linear on x (f32 math, f16 output) ----------
__global__ __launch_bounds__(256) void k_lin(const float* __restrict__ h,
                                             const float* __restrict__ W,
                                             unsigned short* __restrict__ m16) {
    __shared__ float Wl[HD * HD];
    for (int i = threadIdx.x; i < HD * HD; i += 256) Wl[i] = W[i];
    __syncthreads();
    int lane = threadIdx.x & 63, wid = threadIdx.x >> 6;
    int step = gridDim.x * 4;
    for (int n = blockIdx.x * 4 + wid; n < NN; n += step) {
        float hv = h[(size_t)n * HD + lane];
        float acc = 0.f;
        #pragma unroll
        for (int k = 0; k < HD; ++k)
            acc = fmaf(__shfl(hv, k, 64), Wl[k * HD + lane], acc);
        m16[(size_t)n * HD + lane] = f2h(acc);
    }
}

// ---------- edge-parallel segmented gather (f16 messages, f32 accumulate) ----------
__global__ __launch_bounds__(256) void k_gather(const unsigned short* __restrict__ m16,
                                                const int2* __restrict__ epack,
                                                float* __restrict__ agg) {
    int gw = (int)((blockIdx.x * 256 + threadIdx.x) >> 6);
    int lane = threadIdx.x & 63;
    int nw = (gridDim.x * 256) >> 6;
    int per = (NE + nw - 1) / nw;
    int s = gw * per;
    int e = s + per; if (e > NE) e = NE;
    if (s >= NE) return;

    float acc = 0.f;
    int cur = epack[s].y;
    int i = s;
    for (; i + 4 <= e; i += 4) {
        int2 p0 = epack[i], p1 = epack[i + 1], p2 = epack[i + 2], p3 = epack[i + 3];
        float v0 = h2f(m16[(size_t)p0.x * HD + lane]);
        float v1 = h2f(m16[(size_t)p1.x * HD + lane]);
        float v2 = h2f(m16[(size_t)p2.x * HD + lane]);
        float v3 = h2f(m16[(size_t)p3.x * HD + lane]);
        if (p0.y != cur) { atomicAdd(&agg[(size_t)cur * HD + lane], acc); acc = 0.f; cur = p0.y; }
        acc += v0;
        if (p1.y != cur) { atomicAdd(&agg[(size_t)cur * HD + lane], acc); acc = 0.f; cur = p1.y; }
        acc += v1;
        if (p2.y != cur) { atomicAdd(&agg[(size_t)cur * HD + lane], acc); acc = 0.f; cur = p2.y; }
        acc += v2;
        if (p3.y != cur) { atomicAdd(&agg[(size_t)cur * HD + lane], acc); acc = 0.f; cur = p3.y; }
        acc += v3;
    }
    for (; i < e; ++i) {
        int2 p = epack[i];
        float v = h2f(m16[(size_t)p.x * HD + lane]);
        if (p.y != cur) { atomicAdd(&agg[(size_t)cur * HD + lane], acc); acc = 0.f; cur = p.y; }
        acc += v;
    }
    atomicAdd(&agg[(size_t)cur * HD + lane], acc);
}

// ---------- fused cell: gi + gh + GRU + next-layer linear (all f16 dot2) ----------
// WT[kk][j], stride 385: j<192 = pack(Wih[j][2kk],Wih[j][2kk+1]); j>=192 same for Whh.
// WL[kk][c], stride 65:  pack(Wnext[2kk][c], Wnext[2kk+1][c]).
__global__ __launch_bounds__(512) void k_cell(const float* __restrict__ agg,
                                              const float* __restrict__ Wih,
                                              const float* __restrict__ Whh,
                                              const float* __restrict__ bih,
                                              const float* __restrict__ bhh,
                                              const float* __restrict__ h_in,
                                              float* __restrict__ h_out,
                                              const float* __restrict__ Wnext,
                                              unsigned short* __restrict__ m16_next,
                                              int has_next) {
    __shared__ unsigned WT[32 * 385];
    __shared__ unsigned WL[32 * 65];
    const float2* A2 = (const float2*)Wih;   // [192][32] float2
    const float2* H2 = (const float2*)Whh;
    for (int i = threadIdx.x; i < 192 * 32; i += 512) {
        int j = i >> 5, kk = i & 31;
        float2 w = A2[i];
        WT[kk * 385 + j] = pkh2(w.x, w.y);
    }
    for (int i = threadIdx.x; i < 192 * 32; i += 512) {
        int j = i >> 5, kk = i & 31;
        float2 w = H2[i];
        WT[kk * 385 + 192 + j] = pkh2(w.x, w.y);
    }
    if (has_next)
        for (int i = threadIdx.x; i < 32 * 64; i += 512) {
            int kk = i >> 6, c = i & 63;
            WL[kk * 65 + c] = pkh2(Wnext[(2 * kk) * HD + c], Wnext[(2 * kk + 1) * HD + c]);
        }
    __syncthreads();

    int lane = threadIdx.x & 63, wid = threadIdx.x >> 6;
    int gw = blockIdx.x * 8 + wid;
    const int nwaves = gridDim.x * 8;
    float bi0 = bih[lane], bi1 = bih[64 + lane], bi2 = bih[128 + lane];
    float bh0 = bhh[lane], bh1 = bhh[64 + lane], bh2 = bhh[128 + lane];

    for (int n = gw; n < NN; n += nwaves) {
        float av = agg[(size_t)n * HD + lane];
        float hv = h_in[(size_t)n * HD + lane];
        unsigned apk = pkh2(av, __shfl_xor(av, 1, 64));
        unsigned hpk = pkh2(hv, __shfl_xor(hv, 1, 64));

        float a0 = bi0, a1 = bi1, a2 = bi2;
        float g0 = bh0, g1 = bh1, g2 = bh2;
        #pragma unroll 8
        for (int kk = 0; kk < 32; ++kk) {
            unsigned au = rlu(apk, 2 * kk);
            unsigned hu = rlu(hpk, 2 * kk);
            const unsigned* w = &WT[kk * 385];
            a0 = dot2(a0, au, w[lane]);
            a1 = dot2(a1, au, w[64 + lane]);
            a2 = dot2(a2, au, w[128 + lane]);
            g0 = dot2(g0, hu, w[192 + lane]);
            g1 = dot2(g1, hu, w[256 + lane]);
            g2 = dot2(g2, hu, w[320 + lane]);
        }

        float r = 1.f / (1.f + expf(-(a0 + g0)));
        float z = 1.f / (1.f + expf(-(a1 + g1)));
        float nq = tanhf(a2 + r * g2);
        float hnew = (1.f - z) * nq + z * hv;
        h_out[(size_t)n * HD + lane] = hnew;

        if (has_next) {
            unsigned npk = pkh2(hnew, __shfl_xor(hnew, 1, 64));
            float acc = 0.f;
            #pragma unroll 8
            for (int kk = 0; kk < 32; ++kk)
                acc = dot2(acc, rlu(npk, 2 * kk), WL[kk * 65 + lane]);
            m16_next[(size_t)n * HD + lane] = f2h(acc);
        }
    }
}

// ---------- pool ----------
__global__ __launch_bounds__(256) void k_pool(const float* __restrict__ h,
                                              const int* __restrict__ batch,
                                              float* __restrict__ out) {
    int gw = (int)((blockIdx.x * 256 + threadIdx.x) >> 6);
    int lane = threadIdx.x & 63;
    int nw = (gridDim.x * 256) >> 6;
    int per = (NN + nw - 1) / nw;
    int s = gw * per;
    int e = s + per; if (e > NN) e = NN;
    if (s >= NN) return;
    float acc = 0.f;
    int cur = batch[s];
    for (int n = s; n < e; ++n) {
        int b = batch[n];
        if (b != cur) {
            atomicAdd(&out[cur * HD + lane], acc);
            acc = 0.f; cur = b;
        }
        acc += h[n * HD + lane];
    }
    atomicAdd(&out[cur * HD + lane], acc);
}

extern "C" void kernel_launch(void* const* d_in, const int* in_sizes, int n_in,
                              void* d_out, int out_size, void* d_ws, size_t ws_size,
                              hipStream_t stream) {
    const float* x      = (const float*)d_in[0];
    const int*   ei     = (const int*)d_in[1];
    const int*   batch  = (const int*)d_in[2];
    const float* weight = (const float*)d_in[3];
    const float* Wih    = (const float*)d_in[4];
    const float* Whh    = (const float*)d_in[5];
    const float* bih    = (const float*)d_in[6];
    const float* bhh    = (const float*)d_in[7];
    float* out = (float*)d_out;

    char* ws = (char*)d_ws;
    const size_t szH = (size_t)NN * HD * sizeof(float);          // 25.6 MB
    const size_t szM = (size_t)NN * HD * sizeof(unsigned short); // 12.8 MB
    float*          H    = (float*)(ws);
    float*          AG   = (float*)(ws + szH);
    unsigned short* M16  = (unsigned short*)(ws + 2 * szH);
    int*   deg    = (int*)(ws + 2 * szH + szM);
    int*   cursor = deg + NN;
    int*   bsum   = cursor + NN;
    int2*  epack  = (int2*)(bsum + NSB + 2);                     // 12.8 MB

    // CSR build
    hipMemsetAsync(deg, 0, NN * sizeof(int), stream);
    k_deg<<<2048, 256, 0, stream>>>(ei, deg);
    k_scan_a<<<NSB, 1024, 0, stream>>>(deg, cursor, bsum);
    k_scan_b<<<1, 128, 0, stream>>>(bsum);
    k_scan_c<<<NSB, 1024, 0, stream>>>(cursor, bsum);
    k_fill<<<2048, 256, 0, stream>>>(ei, cursor, epack);

    // layer 0
    k_lin<<<1024, 256, 0, stream>>>(x, weight, M16);
    hipMemsetAsync(AG, 0, szH, stream);
    k_gather<<<2048, 256, 0, stream>>>(M16, epack, AG);
    k_cell<<<512, 512, 0, stream>>>(AG, Wih, Whh, bih, bhh, x, H,
                                    weight + HD * HD, M16, 1);
    // layer 1
    hipMemsetAsync(AG, 0, szH, stream);
    k_gather<<<2048, 256, 0, stream>>>(M16, epack, AG);
    k_cell<<<512, 512, 0, stream>>>(AG, Wih, Whh, bih, bhh, H, H,
                                    weight + 2 * HD * HD, M16, 1);
    // layer 2
    hipMemsetAsync(AG, 0, szH, stream);
    k_gather<<<2048, 256, 0, stream>>>(M16, epack, AG);
    k_cell<<<512, 512, 0, stream>>>(AG, Wih, Whh, bih, bhh, H, H,
                                    nullptr, nullptr, 0);

    hipMemsetAsync(out, 0, (size_t)NG * HD * sizeof(float), stream);
    k_pool<<<512, 256, 0, stream>>>(H, batch, out);
}